// Round 5
// baseline (398.047 us; speedup 1.0000x reference)
//
#include <hip/hip_runtime.h>
#include <hip/hip_bf16.h>
#include <stdint.h>

// 2-layer LSTM (H=64) fused over T=336, B=4096, + final linear->sigmoid.
// INTRA-WAVE overlap version: 4 waves/block; wave w owns j-slice
// [16w,16w+16) of BOTH layers, layer-pipelined by one step:
//   A: {ds_reads for L0(i)} + {nonlin gates1(i-2) -> h1(i-2), write}  then 12 L0-MFMA
//   B: {frag reads}         + {nonlin gates0(i)   -> h0(i),  write}  then 16 L1-MFMA
// The VALU nonlin chain and the MFMA burst inside each interval are data-
// independent, so EACH WAVE's own stream keeps both pipes busy -> no reliance
// on wave->SIMD pairing (which R4 showed we cannot control).
// h0 double-buffered, h1 single-buffered; gates carried in regs across barriers.

typedef __attribute__((ext_vector_type(8))) short s16x8;
typedef __attribute__((ext_vector_type(4))) short s16x4;
typedef __attribute__((ext_vector_type(4))) float f32x4;

#define MFMA_BF16 __builtin_amdgcn_mfma_f32_16x16x32_bf16
#define LOG2E     1.4426950408889634f
#define TWO_LOG2E 2.8853900817779268f

__device__ __forceinline__ short f2bf(float f) {
    uint32_t u = __builtin_bit_cast(uint32_t, f);
    u += 0x7fffu + ((u >> 16) & 1u);   // round-to-nearest-even
    return (short)(u >> 16);
}

__device__ __forceinline__ s16x4 pack_bf16x4(float a, float b, float c, float d) {
    union { uint32_t u[2]; s16x4 s; } r;
    asm("v_cvt_pk_bf16_f32 %0, %1, %2" : "=v"(r.u[0]) : "v"(a), "v"(b));
    asm("v_cvt_pk_bf16_f32 %0, %1, %2" : "=v"(r.u[1]) : "v"(c), "v"(d));
    return r.s;
}

// rcp(1 + 2^t): sigma(x) with t = -x*log2e ; tanh via t = 2x*log2e
__device__ __forceinline__ float rcp1p2(float t) {
    return __builtin_amdgcn_rcpf(1.0f + __builtin_amdgcn_exp2f(t));
}

__global__ __launch_bounds__(256, 1)
void lstm_fused(const float* __restrict__ x,
                const float* __restrict__ w_ih0, const float* __restrict__ w_hh0,
                const float* __restrict__ b_ih0, const float* __restrict__ b_hh0,
                const float* __restrict__ w_ih1, const float* __restrict__ w_hh1,
                const float* __restrict__ b_ih1, const float* __restrict__ b_hh1,
                const float* __restrict__ w_lin, const float* __restrict__ b_lin,
                float* __restrict__ out)
{
    __shared__ __align__(16) short xs[16 * 512];        // 16 KB x-chunk
    __shared__ __align__(16) short h0s[2][16 * 64];     // h0 double buffer
    __shared__ __align__(16) short h1s[16 * 64];        // h1 single buffer
    __shared__ float red[4][16];

    const int tid  = threadIdx.x;
    const int w    = tid >> 6;       // wave 0..3: owns j-slice [16w,16w+16) of BOTH layers
    const int l    = tid & 63;
    const int bcol = l & 15;
    const int q    = l >> 4;
    const int b0   = blockIdx.x * 16;

    for (int i = tid; i < 16 * 512; i += 256) xs[i] = 0;
    for (int i = tid; i < 16 * 64; i += 256) {
        h0s[0][i] = 0; h0s[1][i] = 0; h1s[i] = 0;
    }
    __syncthreads();

    // sigma(x)=rcp(1+exp2(-x*log2e)); tanh(x)=1-2*rcp(1+exp2(2x*log2e))
    const float scm[4] = { -LOG2E, -LOG2E, TWO_LOG2E, -LOG2E };

    s16x8 aW0[4][3];     // L0: kf0 = W_ih0 (K 9->32 pad), kf1/2 = W_hh0
    s16x8 aW1[4][4];     // L1: kf0..3 = [W_ih1 | W_hh1]
    f32x4 bias0[4], bias1[4];
    #pragma unroll
    for (int m = 0; m < 4; ++m) {
        const int R = m * 64 + w * 16 + bcol;
        const float sc = scm[m];
        #pragma unroll
        for (int r = 0; r < 8; ++r) {
            int k = q * 8 + r;
            aW0[m][0][r] = (k < 9) ? f2bf(w_ih0[R * 9 + k] * sc) : (short)0;
        }
        #pragma unroll
        for (int kf = 0; kf < 2; ++kf) {
            const float* p = w_hh0 + R * 64 + kf * 32 + q * 8;
            #pragma unroll
            for (int r = 0; r < 8; ++r) aW0[m][1 + kf][r] = f2bf(p[r] * sc);
        }
        #pragma unroll
        for (int kf = 0; kf < 4; ++kf) {
            int ks = kf * 32 + q * 8;
            const float* p = (ks < 64) ? (w_ih1 + R * 64 + ks)
                                       : (w_hh1 + R * 64 + (ks - 64));
            #pragma unroll
            for (int r = 0; r < 8; ++r) aW1[m][kf][r] = f2bf(p[r] * sc);
        }
        #pragma unroll
        for (int r = 0; r < 4; ++r) {
            int G = m * 64 + w * 16 + q * 4 + r;
            bias0[m][r] = (b_ih0[G] + b_hh0[G]) * sc;
            bias1[m][r] = (b_ih1[G] + b_hh1[G]) * sc;
        }
    }

    f32x4 c0 = {0.f,0.f,0.f,0.f}, c1 = {0.f,0.f,0.f,0.f};
    f32x4 h1q = {0.f,0.f,0.f,0.f};
    f32x4 accL1[4];
    #pragma unroll
    for (int m = 0; m < 4; ++m) accL1[m] = (f32x4){0.f,0.f,0.f,0.f};

    const int hrd0 = bcol * 64 + (((q    ) ^ (bcol & 7)) << 3);
    const int hrd1 = bcol * 64 + (((4 + q) ^ (bcol & 7)) << 3);
    const int hwr  = bcol * 64 + (((w * 2 + (q >> 1)) ^ (bcol & 7)) << 3)
                   + ((q & 1) << 2);
    const int xrd  = bcol * 32 + ((q ^ (bcol & 3)) << 3);

    const int    ld_b = tid >> 4, ld_t = tid & 15;
    const float* xrow = x + (size_t)(b0 + ld_b) * (336 * 9) + ld_t * 9;
    const int    xs_wr_base = ld_t * 512 + ld_b * 32;
    const int    xswzw = (ld_b & 3) << 3;

    #pragma unroll 1
    for (int i = 0; i <= 337; ++i) {
        if ((i & 15) == 0 && i < 336) {
            const float* xp = xrow + (size_t)i * 9;
            #pragma unroll
            for (int d = 0; d < 9; ++d)
                xs[(xs_wr_base + d) ^ xswzw] = f2bf(xp[d]);
            __syncthreads();
        }

        const bool doL0 = (i <= 335);
        const bool rdH0 = (i <= 336);
        const bool doL1 = (i >= 1 && i <= 336);

        // ================ interval A ================
        s16x8 bx, ba, bb;
        if (doL0) bx = *(const s16x8*)&xs[(i & 15) * 512 + xrd];
        if (rdH0) {
            const short* h0r = h0s[(i & 1) ^ 1];               // h0(i-1)
            ba = *(const s16x8*)&h0r[hrd0];
            bb = *(const s16x8*)&h0r[hrd1];
        }
        if (i >= 2) {   // nonlin gates1(i-2) -> h1(i-2)   [VALU, fills read/MFMA time]
            #pragma unroll
            for (int r = 0; r < 4; ++r) {
                float iv = rcp1p2(accL1[0][r]);
                float fv = rcp1p2(accL1[1][r]);
                float gv = fmaf(-2.f, rcp1p2(accL1[2][r]), 1.f);
                float ov = rcp1p2(accL1[3][r]);
                float cc = fv * c1[r] + iv * gv;
                c1[r] = cc;
                h1q[r] = ov * fmaf(-2.f, rcp1p2(cc * TWO_LOG2E), 1.f);
            }
            *(s16x4*)&h1s[hwr] = pack_bf16x4(h1q[0], h1q[1], h1q[2], h1q[3]);
        }
        f32x4 acc0[4];
        if (doL0) {     // 12 MFMA: gates0(i)
            #pragma unroll
            for (int m = 0; m < 4; ++m) acc0[m] = MFMA_BF16(aW0[m][0], bx, bias0[m], 0, 0, 0);
            #pragma unroll
            for (int m = 0; m < 4; ++m) acc0[m] = MFMA_BF16(aW0[m][1], ba, acc0[m], 0, 0, 0);
            #pragma unroll
            for (int m = 0; m < 4; ++m) acc0[m] = MFMA_BF16(aW0[m][2], bb, acc0[m], 0, 0, 0);
        }
        __syncthreads();   // h1(i-2) visible

        // ================ interval B ================
        s16x8 b1a, b1b;
        if (doL1) {
            b1a = *(const s16x8*)&h1s[hrd0];                   // h1(i-2)
            b1b = *(const s16x8*)&h1s[hrd1];
        }
        if (doL0) {     // nonlin gates0(i) -> h0(i)   [VALU, overlaps L1 MFMA below]
            #pragma unroll
            for (int r = 0; r < 4; ++r) {
                float iv = rcp1p2(acc0[0][r]);
                float fv = rcp1p2(acc0[1][r]);
                float gv = fmaf(-2.f, rcp1p2(acc0[2][r]), 1.f);
                float ov = rcp1p2(acc0[3][r]);
                float cc = fv * c0[r] + iv * gv;
                c0[r] = cc;
                float hh = ov * fmaf(-2.f, rcp1p2(cc * TWO_LOG2E), 1.f);
                acc0[0][r] = hh;                                // reuse as h0q
            }
            short* h0w = h0s[i & 1];
            *(s16x4*)&h0w[hwr] = pack_bf16x4(acc0[0][0], acc0[0][1], acc0[0][2], acc0[0][3]);
        }
        if (doL1) {     // 16 MFMA: gates1(i-1) from h0(i-1), h1(i-2)
            #pragma unroll
            for (int m = 0; m < 4; ++m) accL1[m] = MFMA_BF16(aW1[m][0], ba,  bias1[m], 0, 0, 0);
            #pragma unroll
            for (int m = 0; m < 4; ++m) accL1[m] = MFMA_BF16(aW1[m][1], bb,  accL1[m], 0, 0, 0);
            #pragma unroll
            for (int m = 0; m < 4; ++m) accL1[m] = MFMA_BF16(aW1[m][2], b1a, accL1[m], 0, 0, 0);
            #pragma unroll
            for (int m = 0; m < 4; ++m) accL1[m] = MFMA_BF16(aW1[m][3], b1b, accL1[m], 0, 0, 0);
        }
        __syncthreads();   // h0(i) visible
    }

    // ---- out[b] = sigm(sum_j h1_335[b][j] * w_lin[j] + b_lin) ----
    {
        float part = h1q[0] * w_lin[w * 16 + q * 4 + 0]
                   + h1q[1] * w_lin[w * 16 + q * 4 + 1]
                   + h1q[2] * w_lin[w * 16 + q * 4 + 2]
                   + h1q[3] * w_lin[w * 16 + q * 4 + 3];
        part += __shfl_xor(part, 16, 64);
        part += __shfl_xor(part, 32, 64);
        if (q == 0) red[w][bcol] = part;
    }
    __syncthreads();
    if (tid < 16) {
        float s = red[0][tid] + red[1][tid] + red[2][tid] + red[3][tid] + b_lin[0];
        out[b0 + tid] = rcp1p2(-s * LOG2E);
    }
}

extern "C" void kernel_launch(void* const* d_in, const int* in_sizes, int n_in,
                              void* d_out, int out_size, void* d_ws, size_t ws_size,
                              hipStream_t stream) {
    const float* x     = (const float*)d_in[0];
    const float* w_ih0 = (const float*)d_in[1];
    const float* w_hh0 = (const float*)d_in[2];
    const float* b_ih0 = (const float*)d_in[3];
    const float* b_hh0 = (const float*)d_in[4];
    const float* w_ih1 = (const float*)d_in[5];
    const float* w_hh1 = (const float*)d_in[6];
    const float* b_ih1 = (const float*)d_in[7];
    const float* b_hh1 = (const float*)d_in[8];
    const float* w_lin = (const float*)d_in[9];
    const float* b_lin = (const float*)d_in[10];

    lstm_fused<<<dim3(256), dim3(256), 0, stream>>>(
        x, w_ih0, w_hh0, b_ih0, b_hh0,
        w_ih1, w_hh1, b_ih1, b_hh1,
        w_lin, b_lin, (float*)d_out);
}

// Round 6
// 372.708 us; speedup vs baseline: 1.0680x; 1.0680x over previous
//
#include <hip/hip_runtime.h>
#include <hip/hip_bf16.h>
#include <stdint.h>

// 2-layer LSTM (H=64) fused over T=336, B=4096, + final linear->sigmoid.
// 16-wave (1024-thr) GATE-GATHER version: per block 16 batches.
//  Phase M: 16 waves each compute 2 gate tiles (L0: waves 0-7, 6 MFMA;
//           L1: waves 8-15, 8 MFMA) and write f32 pre-activations to LDS.
//  Phase N: nonlinearity redistributed over ALL 1024 lanes (2 h-elements
//           per lane, c fp32 in regs), h written bf16 to LDS.
// 4 waves/SIMD to fill the lockstep stall windows that capped R2-R4.
// exp-scales folded into weights: sigma = rcp(1+exp2(pre)).

typedef __attribute__((ext_vector_type(8))) short s16x8;
typedef __attribute__((ext_vector_type(4))) float f32x4;

#define MFMA_BF16 __builtin_amdgcn_mfma_f32_16x16x32_bf16
#define LOG2E     1.4426950408889634f
#define TWO_LOG2E 2.8853900817779268f

__device__ __forceinline__ short f2bf(float f) {
    uint32_t u = __builtin_bit_cast(uint32_t, f);
    u += 0x7fffu + ((u >> 16) & 1u);   // round-to-nearest-even
    return (short)(u >> 16);
}

// rcp(1 + 2^t): sigma(x) with t = -x*log2e ; tanh via t = 2x*log2e
__device__ __forceinline__ float rcp1p2(float t) {
    return __builtin_amdgcn_rcpf(1.0f + __builtin_amdgcn_exp2f(t));
}

__global__ __launch_bounds__(1024, 4)
void lstm_fused(const float* __restrict__ x,
                const float* __restrict__ w_ih0, const float* __restrict__ w_hh0,
                const float* __restrict__ b_ih0, const float* __restrict__ b_hh0,
                const float* __restrict__ w_ih1, const float* __restrict__ w_hh1,
                const float* __restrict__ b_ih1, const float* __restrict__ b_hh1,
                const float* __restrict__ w_lin, const float* __restrict__ b_lin,
                float* __restrict__ out)
{
    __shared__ __align__(16) short xs[16 * 512];     // 16 KB x-chunk (bf16, K-padded)
    __shared__ __align__(16) float gbuf[8192];       // 32 KB gate pre-acts f32
    __shared__ __align__(16) short h0s[16 * 64];     // 2 KB h0 bf16
    __shared__ __align__(16) short h1s[16 * 64];     // 2 KB h1 bf16
    __shared__ float red[8][16];

    const int tid  = threadIdx.x;
    const int w    = tid >> 6;       // wave 0..15
    const int l    = tid & 63;
    const int bcol = l & 15;
    const int q    = l >> 4;
    const int b0   = blockIdx.x * 16;

    for (int i = tid; i < 16 * 512; i += 1024) xs[i] = 0;
    for (int i = tid; i < 16 * 64; i += 1024) { h0s[i] = 0; h1s[i] = 0; }
    __syncthreads();

    // ---------- MFMA-role: layer Lw, gate-pair gp, j-slice js ----------
    const int Lw = w >> 3;           // 0: layer0, 1: layer1
    const int gp = (w >> 2) & 1;     // gates {2gp, 2gp+1}
    const int js = w & 3;            // j in [16js, 16js+16)

    // sigma(x)=rcp(1+exp2(-x*log2e)); tanh(x)=1-2*rcp(1+exp2(2x*log2e))
    const float scm[4] = { -LOG2E, -LOG2E, TWO_LOG2E, -LOG2E };

    s16x8 aW[2][4];                  // [tile tt][kf]
    f32x4 bias[2];
    #pragma unroll
    for (int tt = 0; tt < 2; ++tt) {
        const int m  = 2 * gp + tt;
        const int R  = m * 64 + js * 16 + bcol;       // weight row
        const float sc = scm[m];
        if (Lw == 0) {
            #pragma unroll
            for (int r = 0; r < 8; ++r) {
                int k = q * 8 + r;
                aW[tt][0][r] = (k < 9) ? f2bf(w_ih0[R * 9 + k] * sc) : (short)0;
            }
            #pragma unroll
            for (int kf = 0; kf < 2; ++kf) {
                const float* p = w_hh0 + R * 64 + kf * 32 + q * 8;
                #pragma unroll
                for (int r = 0; r < 8; ++r) aW[tt][1 + kf][r] = f2bf(p[r] * sc);
            }
        } else {
            #pragma unroll
            for (int kf = 0; kf < 4; ++kf) {
                int ks = kf * 32 + q * 8;
                const float* p = (ks < 64) ? (w_ih1 + R * 64 + ks)
                                           : (w_hh1 + R * 64 + (ks - 64));
                #pragma unroll
                for (int r = 0; r < 8; ++r) aW[tt][kf][r] = f2bf(p[r] * sc);
            }
        }
        const float* bi = (Lw == 0) ? b_ih0 : b_ih1;
        const float* bh = (Lw == 0) ? b_hh0 : b_hh1;
        #pragma unroll
        for (int r = 0; r < 4; ++r) {
            int G = m * 64 + js * 16 + q * 4 + r;     // C row = q*4+r
            bias[tt][r] = (bi[G] + bh[G]) * sc;
        }
    }

    // h frag reads (B-operand): 8 shorts at k = q*8..q*8+7 (+32 for the b-half)
    const int hrd0 = bcol * 64 + (((q    ) ^ (bcol & 7)) << 3);
    const int hrd1 = bcol * 64 + (((4 + q) ^ (bcol & 7)) << 3);
    const int xrd  = bcol * 32 + ((q ^ (bcol & 3)) << 3);

    // ---------- nonlin-role: layer Ln, element pair (bn, j0), (bn, j0+1) ----------
    const int Ln = w >> 3;
    const int bn = l & 15;
    const int j0 = 2 * ((w & 7) * 4 + (l >> 4));      // even
    // gbuf float index: L*4096 + b*256 + ((j ^ (b&7))<<2) + m
    const int g_rd0 = Ln * 4096 + bn * 256 + (((j0    ) ^ (bn & 7)) << 2);
    const int g_rd1 = Ln * 4096 + bn * 256 + (((j0 + 1) ^ (bn & 7)) << 2);
    const int h_wr  = bn * 64 + (((j0 >> 3) ^ (bn & 7)) << 3) + (j0 & 7);
    short* const hws = (Ln == 0) ? h0s : h1s;

    float cA = 0.f, cB = 0.f;        // cell state for the 2 owned elements
    float hA = 0.f, hB = 0.f;        // last h (L1 lanes keep h1_335)
    const float wl0 = w_lin[j0], wl1 = w_lin[j0 + 1];

    const int    ld_b = tid >> 4, ld_t = tid & 15;    // staging (tid<256 only)
    const float* xrow = x + (size_t)(b0 + ld_b) * (336 * 9) + ld_t * 9;
    const int    xs_wr_base = ld_t * 512 + ld_b * 32;
    const int    xswzw = (ld_b & 3) << 3;

    #pragma unroll 1
    for (int i = 0; i <= 336; ++i) {
        if ((i & 15) == 0 && i < 336) {
            if (tid < 256) {
                const float* xp = xrow + (size_t)i * 9;
                #pragma unroll
                for (int d = 0; d < 9; ++d)
                    xs[(xs_wr_base + d) ^ xswzw] = f2bf(xp[d]);
            }
            __syncthreads();
        }

        // ================= phase M: MFMA + gate scatter =================
        const bool mAct = (Lw == 0) ? (i <= 335) : (i >= 1);
        if (mAct) {
            f32x4 a0 = bias[0], a1 = bias[1];
            if (Lw == 0) {
                s16x8 bx = *(const s16x8*)&xs[(i & 15) * 512 + xrd];
                s16x8 ba = *(const s16x8*)&h0s[hrd0];   // h0(i-1)
                s16x8 bb = *(const s16x8*)&h0s[hrd1];
                a0 = MFMA_BF16(aW[0][0], bx, a0, 0, 0, 0);
                a1 = MFMA_BF16(aW[1][0], bx, a1, 0, 0, 0);
                a0 = MFMA_BF16(aW[0][1], ba, a0, 0, 0, 0);
                a1 = MFMA_BF16(aW[1][1], ba, a1, 0, 0, 0);
                a0 = MFMA_BF16(aW[0][2], bb, a0, 0, 0, 0);
                a1 = MFMA_BF16(aW[1][2], bb, a1, 0, 0, 0);
            } else {
                s16x8 ba  = *(const s16x8*)&h0s[hrd0];  // h0(i-1)
                s16x8 bb  = *(const s16x8*)&h0s[hrd1];
                s16x8 b1a = *(const s16x8*)&h1s[hrd0];  // h1(i-2)
                s16x8 b1b = *(const s16x8*)&h1s[hrd1];
                a0 = MFMA_BF16(aW[0][0], ba,  a0, 0, 0, 0);
                a1 = MFMA_BF16(aW[1][0], ba,  a1, 0, 0, 0);
                a0 = MFMA_BF16(aW[0][1], bb,  a0, 0, 0, 0);
                a1 = MFMA_BF16(aW[1][1], bb,  a1, 0, 0, 0);
                a0 = MFMA_BF16(aW[0][2], b1a, a0, 0, 0, 0);
                a1 = MFMA_BF16(aW[1][2], b1a, a1, 0, 0, 0);
                a0 = MFMA_BF16(aW[0][3], b1b, a0, 0, 0, 0);
                a1 = MFMA_BF16(aW[1][3], b1b, a1, 0, 0, 0);
            }
            // scatter: gbuf[Lw][bcol][j = js*16+q*4+r][m = 2gp + (0|1)]
            #pragma unroll
            for (int r = 0; r < 4; ++r) {
                int j    = js * 16 + q * 4 + r;
                int fidx = Lw * 4096 + bcol * 256 + ((j ^ (bcol & 7)) << 2) + 2 * gp;
                float2 v = { a0[r], a1[r] };
                *(float2*)&gbuf[fidx] = v;
            }
        }
        __syncthreads();   // gates(i) visible; all h reads of phase M done

        // ================= phase N: nonlinearity (all 1024 lanes) =================
        const bool nAct = (Ln == 0) ? (i <= 335) : (i >= 1);
        if (nAct) {
            f32x4 gA = *(const f32x4*)&gbuf[g_rd0];
            f32x4 gB = *(const f32x4*)&gbuf[g_rd1];
            {
                float iv = rcp1p2(gA[0]);
                float fv = rcp1p2(gA[1]);
                float gv = fmaf(-2.f, rcp1p2(gA[2]), 1.f);
                float ov = rcp1p2(gA[3]);
                cA = fv * cA + iv * gv;
                hA = ov * fmaf(-2.f, rcp1p2(cA * TWO_LOG2E), 1.f);
            }
            {
                float iv = rcp1p2(gB[0]);
                float fv = rcp1p2(gB[1]);
                float gv = fmaf(-2.f, rcp1p2(gB[2]), 1.f);
                float ov = rcp1p2(gB[3]);
                cB = fv * cB + iv * gv;
                hB = ov * fmaf(-2.f, rcp1p2(cB * TWO_LOG2E), 1.f);
            }
            uint32_t p;
            asm("v_cvt_pk_bf16_f32 %0, %1, %2" : "=v"(p) : "v"(hA), "v"(hB));
            *(uint32_t*)&hws[h_wr] = p;
        }
        __syncthreads();   // h0(i)/h1(i-1) visible; gate reads done before next M
    }

    // ---- out[b] = sigm(sum_j h1_335[b][j] * w_lin[j] + b_lin) ----
    if (Ln == 1) {
        float part = hA * wl0 + hB * wl1;
        part += __shfl_xor(part, 16, 64);
        part += __shfl_xor(part, 32, 64);
        if (l < 16) red[w & 7][bn] = part;
    }
    __syncthreads();
    if (tid < 16) {
        float s = red[0][tid] + red[1][tid] + red[2][tid] + red[3][tid]
                + red[4][tid] + red[5][tid] + red[6][tid] + red[7][tid] + b_lin[0];
        out[b0 + tid] = rcp1p2(-s * LOG2E);
    }
}

extern "C" void kernel_launch(void* const* d_in, const int* in_sizes, int n_in,
                              void* d_out, int out_size, void* d_ws, size_t ws_size,
                              hipStream_t stream) {
    const float* x     = (const float*)d_in[0];
    const float* w_ih0 = (const float*)d_in[1];
    const float* w_hh0 = (const float*)d_in[2];
    const float* b_ih0 = (const float*)d_in[3];
    const float* b_hh0 = (const float*)d_in[4];
    const float* w_ih1 = (const float*)d_in[5];
    const float* w_hh1 = (const float*)d_in[6];
    const float* b_ih1 = (const float*)d_in[7];
    const float* b_hh1 = (const float*)d_in[8];
    const float* w_lin = (const float*)d_in[9];
    const float* b_lin = (const float*)d_in[10];

    lstm_fused<<<dim3(256), dim3(1024), 0, stream>>>(
        x, w_ih0, w_hh0, b_ih0, b_hh0,
        w_ih1, w_hh1, b_ih1, b_hh1,
        w_lin, b_lin, (float*)d_out);
}